// Round 5
// baseline (225.702 us; speedup 1.0000x reference)
//
#include <hip/hip_runtime.h>

// SpectralMultiHeadAttention on MI355X (gfx950)
// b=4, hw=16384, c=256, heads=8, dh=32.
// Reformulation: S[b] = x^T x (256x256);  G = Wq^T S Wk;  qss = diag(Wq^T S Wq);
// kss = diag(Wk^T S Wk);  A = softmax(G_blocks / (nq nk sqrt(hw)));
// out = x @ (Wv @ Abig^T @ Wout).   q/k/v never materialized.
// R8: chain is latency+overhead dominated (R4: -130MB traffic -> +0.1us;
//     R7: grid/prefetch restructure -> +1us). Attack per-kernel VALU time:
//     (a) f2bf bit-twiddle replaced by native __bf16 cast -> v_cvt_* HW
//         (RNE, bit-identical on finite normals) in k_sgemm staging and
//         k_out A-path, which were VALU-cast-bound (R5: k_sgemm 42.6us at
//         only 20% HBM, 7% MFMA -> issue-bound, cast ~2/3 of staging VALU).
//     (b) k_sgemm LDS double-buffer: ONE barrier per phase instead of two;
//         ds_writes of phase p+1 overlap MFMA reads of phase p.

#define B_   4
#define HW_  16384
#define C_   256

typedef __attribute__((ext_vector_type(8))) short short8;
typedef __attribute__((ext_vector_type(4))) float floatx4;

__device__ __forceinline__ unsigned short f2bf(float f) {
  return __builtin_bit_cast(unsigned short, (__bf16)f);   // v_cvt (RNE)
}

__device__ __forceinline__ void gl_lds16(const unsigned short* g, unsigned short* l) {
  __builtin_amdgcn_global_load_lds(
      (const __attribute__((address_space(1))) unsigned int*)g,
      (__attribute__((address_space(3))) unsigned int*)l, 16, 0, 0);
}

// ---------------------------------------------------------------------------
// K2: S partials. grid 256 = half(1b) | ks(5b) | b(2b), 512 thr. Each block
// stages the FULL 256c x 128hw bf16 panel (4 phases over its 512-hw chunk)
// into DOUBLE-BUFFERED LDS but computes only a 128-row half of the 256x256
// output. XOR-octet swizzle as before. One __syncthreads per phase:
// within a phase, MFMA reads buf[cur] while casts+ds_writes fill buf[nxt]
// (different buffers -> no intra-phase hazard); the end-of-phase barrier
// orders W(nxt)->R(nxt) and R(cur)->W(cur) across phases.
// K order identical to R7 -> S bitwise-same.
// ---------------------------------------------------------------------------
__global__ __launch_bounds__(512) void k_sgemm(const float* __restrict__ x,
                                               float* __restrict__ part) {
  __shared__ unsigned short Pt[2][256 * 128];   // 128 KiB
  int bid = blockIdx.x;
  int hs = bid & 1, ks = (bid >> 1) & 31, b = bid >> 6;
  const float* xv = x + ((size_t)(b * HW_ + ks * 512)) * C_;
  int t = threadIdx.x, lane = t & 63, w = t >> 6;   // 8 waves
  int rw = w >> 2, cw = w & 3;                      // 2x4 wave grid on 128x256
  int m0 = hs * 128 + rw * 64;
  int n0 = cw * 64;
  int l15 = lane & 15, l4 = lane >> 4;
  int s_cq  = (lane >> 3) | (w << 3);       // 0..63: which c-quad
  int s_hpl = lane & 7;                     // low 3 bits of hw-pair
  floatx4 acc[4][4];
  floatx4 z = {0.f, 0.f, 0.f, 0.f};
#pragma unroll
  for (int i = 0; i < 4; i++)
#pragma unroll
    for (int j = 0; j < 4; j++) acc[i][j] = z;

  // stage phase 0 into Pt[0] (load -> cvt -> ds_write)
#pragma unroll
  for (int e = 0; e < 8; e++) {
    int hp = s_hpl | (e << 3);
    const float* src = xv + ((size_t)(hp * 2)) * C_ + s_cq * 4;
    float4 v0 = *(const float4*)src;
    float4 v1 = *(const float4*)(src + C_);
    float a0[4] = {v0.x, v0.y, v0.z, v0.w};
    float a1[4] = {v1.x, v1.y, v1.z, v1.w};
#pragma unroll
    for (int i = 0; i < 4; i++) {
      unsigned u = (unsigned)f2bf(a0[i]) | ((unsigned)f2bf(a1[i]) << 16);
      int r = s_cq * 4 + i;
      int slot = (hp >> 2) ^ (r & 15);
      ((unsigned*)Pt[0])[r * 64 + slot * 4 + (hp & 3)] = u;
    }
  }
  __syncthreads();

  float4 pA[8], pB[8];
  for (int ph = 0; ph < 4; ph++) {
    int cur = ph & 1, nxt = cur ^ 1;
    if (ph < 3) {
      // issue next phase's global loads early (latency under MFMA below)
#pragma unroll
      for (int e = 0; e < 8; e++) {
        int hp = s_hpl | (e << 3);
        const float* src = xv + ((size_t)((ph + 1) * 128 + hp * 2)) * C_ + s_cq * 4;
        pA[e] = *(const float4*)src;
        pB[e] = *(const float4*)(src + C_);
      }
    }
#pragma unroll
    for (int kk = 0; kk < 4; kk++) {       // 4 k-steps of 32 per phase
      short8 af[4], bfv[4];
      int oct = kk * 4 + l4;
#pragma unroll
      for (int tm = 0; tm < 4; tm++) {
        int row = m0 + tm * 16 + l15;
        af[tm] = *(const short8*)(Pt[cur] + row * 128 + ((oct ^ (row & 15)) * 8));
      }
#pragma unroll
      for (int tn = 0; tn < 4; tn++) {
        int row = n0 + tn * 16 + l15;
        bfv[tn] = *(const short8*)(Pt[cur] + row * 128 + ((oct ^ (row & 15)) * 8));
      }
#pragma unroll
      for (int tm = 0; tm < 4; tm++)
#pragma unroll
        for (int tn = 0; tn < 4; tn++)
          acc[tm][tn] = __builtin_amdgcn_mfma_f32_16x16x32_bf16(af[tm], bfv[tn],
                                                                acc[tm][tn], 0, 0, 0);
    }
    if (ph < 3) {
      // cast + write next phase into the OTHER buffer (no hazard with cur)
#pragma unroll
      for (int e = 0; e < 8; e++) {
        int hp = s_hpl | (e << 3);
        float a0[4] = {pA[e].x, pA[e].y, pA[e].z, pA[e].w};
        float a1[4] = {pB[e].x, pB[e].y, pB[e].z, pB[e].w};
#pragma unroll
        for (int i = 0; i < 4; i++) {
          unsigned u = (unsigned)f2bf(a0[i]) | ((unsigned)f2bf(a1[i]) << 16);
          int r = s_cq * 4 + i;
          int slot = (hp >> 2) ^ (r & 15);
          ((unsigned*)Pt[nxt])[r * 64 + slot * 4 + (hp & 3)] = u;
        }
      }
    }
    __syncthreads();                       // one barrier per phase
  }
  // epilogue: streaming fp32 partial half-tile [b][ks][m 128-half][256]
  float* pb = part + (size_t)(b * 32 + ks) * 65536;
#pragma unroll
  for (int tm = 0; tm < 4; tm++)
#pragma unroll
    for (int tn = 0; tn < 4; tn++)
#pragma unroll
      for (int r = 0; r < 4; r++) {
        int m = m0 + tm * 16 + l4 * 4 + r;   // C/D: row=(lane>>4)*4+reg
        int n = n0 + tn * 16 + l15;          //      col=lane&15
        pb[m * 256 + n] = acc[tm][tn][r];
      }
}

// K2r: reduce 32 K-partials -> S fp32 [b][256][256]. grid 256 x 256, float4.
__global__ __launch_bounds__(256) void k_sred(const float* __restrict__ part,
                                              float* __restrict__ S) {
  int g = blockIdx.x * 256 + threadIdx.x;     // 0..65535 float4 slots
  int b = g >> 14, off = (g & 16383) * 4;
  const float* p = part + ((size_t)b << 21) + off;
  float4 s = {0.f, 0.f, 0.f, 0.f};
#pragma unroll
  for (int k = 0; k < 32; k++) {
    float4 v = *(const float4*)(p + ((size_t)k << 16));
    s.x += v.x; s.y += v.y; s.z += v.z; s.w += v.w;
  }
  *(float4*)(S + ((size_t)b << 16) + off) = s;
}

// ---------------------------------------------------------------------------
// K3a: SWq = S@Wq, SWk = S@Wk (fp32, 64x64 tiles). grid 128 = b(4)*mt(4)*nt(8).
// ---------------------------------------------------------------------------
__global__ __launch_bounds__(256) void k_gemm_sw(const float* __restrict__ S,
                                                 const float* __restrict__ Wq,
                                                 const float* __restrict__ Wk,
                                                 float* __restrict__ SWq,
                                                 float* __restrict__ SWk) {
  __shared__ float Ast[16][68];
  __shared__ float Bs[16][68];
  int bid = blockIdx.x;
  int nt = bid & 7, mt = (bid >> 3) & 3, b = bid >> 5;
  int mb = mt * 64;
  const float* Wsel = (nt < 4) ? Wq : Wk;
  int nb = (nt & 3) * 64;
  int t = threadIdx.x, tx = t & 15, ty = t >> 4;
  float acc[4][4] = {};
  for (int kt = 0; kt < 16; kt++) {
    {
      int row = t >> 2, kq = t & 3;
      float4 v = *(const float4*)(S + ((size_t)(b * C_ + mb + row)) * C_ + kt * 16 + kq * 4);
      Ast[kq * 4 + 0][row] = v.x; Ast[kq * 4 + 1][row] = v.y;
      Ast[kq * 4 + 2][row] = v.z; Ast[kq * 4 + 3][row] = v.w;
    }
    {
      int kk = t >> 4, n4 = t & 15;
      float4 v = *(const float4*)(Wsel + ((size_t)(kt * 16 + kk)) * C_ + nb + n4 * 4);
      *(float4*)&Bs[kk][n4 * 4] = v;
    }
    __syncthreads();
#pragma unroll
    for (int k = 0; k < 16; k++) {
      float4 a4 = *(const float4*)&Ast[k][ty * 4];
      float4 b4 = *(const float4*)&Bs[k][tx * 4];
      float a[4] = {a4.x, a4.y, a4.z, a4.w};
      float bb[4] = {b4.x, b4.y, b4.z, b4.w};
#pragma unroll
      for (int i = 0; i < 4; i++)
#pragma unroll
        for (int j = 0; j < 4; j++) acc[i][j] += a[i] * bb[j];
    }
    __syncthreads();
  }
#pragma unroll
  for (int i = 0; i < 4; i++)
#pragma unroll
    for (int j = 0; j < 4; j++) {
      int row = mb + ty * 4 + i;
      int ng = nt * 64 + tx * 4 + j;
      if (ng < 256) SWq[((size_t)(b * C_ + row)) * C_ + ng] = acc[i][j];
      else          SWk[((size_t)(b * C_ + row)) * C_ + ng - 256] = acc[i][j];
    }
}

// ---------------------------------------------------------------------------
// K3f: fused G_h + norms + softmax + U_h. grid 32 = (b,h), 256 thr.
// ---------------------------------------------------------------------------
__global__ __launch_bounds__(256) void k_fuse(const float* __restrict__ Wq,
                                              const float* __restrict__ Wk,
                                              const float* __restrict__ SWq,
                                              const float* __restrict__ SWk,
                                              const float* __restrict__ Wout,
                                              float* __restrict__ U) {
  __shared__ float Wqh[256][32];    // 32 KiB (reused as Wo[32][256] for U phase)
  __shared__ float Wkh[256][32];
  __shared__ float SWqh[256][32];
  __shared__ float SWkh[256][32];   // total 128 KiB
  __shared__ float Lg[32][33];
  __shared__ float qp[8][32], kp[8][32], qin[32], kin[32];
  int b = blockIdx.x >> 3, h = blockIdx.x & 7;
  int t = threadIdx.x;
  int col = t & 31, rgrp = t >> 5;               // 8 rows per sweep
  for (int r0 = 0; r0 < 256; r0 += 8) {
    int row = r0 + rgrp;
    Wqh[row][col]  = Wq[(size_t)row * C_ + h * 32 + col];
    Wkh[row][col]  = Wk[(size_t)row * C_ + h * 32 + col];
    SWqh[row][col] = SWq[((size_t)(b * C_ + row)) * C_ + h * 32 + col];
    SWkh[row][col] = SWk[((size_t)(b * C_ + row)) * C_ + h * 32 + col];
  }
  __syncthreads();
  {
    float g[4] = {0.f, 0.f, 0.f, 0.f};
    for (int k = 0; k < 256; k++) {
      float swk = SWkh[k][col];
#pragma unroll
      for (int r = 0; r < 4; r++) g[r] += Wqh[k][rgrp + 8 * r] * swk;
    }
#pragma unroll
    for (int r = 0; r < 4; r++) Lg[rgrp + 8 * r][col] = g[r];
  }
  {
    float sq = 0.f, sk = 0.f;
    for (int k = rgrp * 32; k < rgrp * 32 + 32; k++) {
      sq += Wqh[k][col] * SWqh[k][col];
      sk += Wkh[k][col] * SWkh[k][col];
    }
    qp[rgrp][col] = sq;
    kp[rgrp][col] = sk;
  }
  __syncthreads();
  if (t < 32) {
    float a = 0.f;
#pragma unroll
    for (int p = 0; p < 8; p++) a += qp[p][t];
    qin[t] = rsqrtf(a);
  } else if (t < 64) {
    int j = t - 32;
    float a = 0.f;
#pragma unroll
    for (int p = 0; p < 8; p++) a += kp[p][j];
    kin[j] = rsqrtf(a);
  }
  __syncthreads();
  if (t < 32) {
    float row[32];
    float mx = -1e30f;
#pragma unroll
    for (int j = 0; j < 32; j++) {
      row[j] = Lg[t][j] * qin[t] * kin[j] * 0.0078125f;   // /sqrt(16384)
      mx = fmaxf(mx, row[j]);
    }
    float sum = 0.f;
#pragma unroll
    for (int j = 0; j < 32; j++) { row[j] = __expf(row[j] - mx); sum += row[j]; }
    float inv = 1.0f / sum;
#pragma unroll
    for (int j = 0; j < 32; j++) Lg[t][j] = row[j] * inv;
  }
  __syncthreads();
  float (*Wo)[256] = reinterpret_cast<float(*)[256]>(&Wqh[0][0]);
#pragma unroll
  for (int r = 0; r < 32; r++) Wo[r][t] = Wout[((size_t)(h * 32 + r)) * C_ + t];
  __syncthreads();
  for (int j = 0; j < 32; j++) {
    float a = 0.f;
#pragma unroll
    for (int i2 = 0; i2 < 32; i2++) a += Lg[i2][j] * Wo[i2][t];
    U[((size_t)(b * C_ + h * 32 + j)) * C_ + t] = a;
  }
}

// ---------------------------------------------------------------------------
// K3e: W3 = Wv @ U[b], emitted transposed bf16: W3bT[b][n][c]. grid 64.
// ---------------------------------------------------------------------------
__global__ __launch_bounds__(256) void k_gemm_w3(const float* __restrict__ Wv,
                                                 const float* __restrict__ U,
                                                 unsigned short* __restrict__ W3bT) {
  __shared__ float Ast[16][68];
  __shared__ float Bs[16][68];
  int bid = blockIdx.x;
  int nt = bid & 3, mt = (bid >> 2) & 3, b = bid >> 4;
  int mb = mt * 64, nb = nt * 64;
  int t = threadIdx.x, tx = t & 15, ty = t >> 4;
  float acc[4][4] = {};
  for (int kt = 0; kt < 16; kt++) {
    {
      int row = t >> 2, kq = t & 3;
      float4 v = *(const float4*)(Wv + ((size_t)(mb + row)) * C_ + kt * 16 + kq * 4);
      Ast[kq * 4 + 0][row] = v.x; Ast[kq * 4 + 1][row] = v.y;
      Ast[kq * 4 + 2][row] = v.z; Ast[kq * 4 + 3][row] = v.w;
    }
    {
      int kk = t >> 4, n4 = t & 15;
      float4 v = *(const float4*)(U + ((size_t)(b * C_ + kt * 16 + kk)) * C_ + nb + n4 * 4);
      *(float4*)&Bs[kk][n4 * 4] = v;
    }
    __syncthreads();
#pragma unroll
    for (int k = 0; k < 16; k++) {
      float4 a4 = *(const float4*)&Ast[k][ty * 4];
      float4 b4 = *(const float4*)&Bs[k][tx * 4];
      float a[4] = {a4.x, a4.y, a4.z, a4.w};
      float bb[4] = {b4.x, b4.y, b4.z, b4.w};
#pragma unroll
      for (int i = 0; i < 4; i++)
#pragma unroll
        for (int j = 0; j < 4; j++) acc[i][j] += a[i] * bb[j];
    }
    __syncthreads();
  }
#pragma unroll
  for (int i = 0; i < 4; i++)
#pragma unroll
    for (int j = 0; j < 4; j++)
      W3bT[((size_t)(b * C_ + nb + tx * 4 + j)) * C_ + mb + ty * 4 + i] = f2bf(acc[i][j]);
}

// ---------------------------------------------------------------------------
// K4: out = x @ W3[b], fp32 out. grid 512 = mtile. BN=256 per block.
// A-fragments read DIRECTLY from fp32 x (L3-hot) + v_cvt cast; B staged
// via swizzled global_load_lds (8-slot rows). BK=64, 4 stages.
// ---------------------------------------------------------------------------
__global__ __launch_bounds__(256) void k_out(const float* __restrict__ x,
                                             const unsigned short* __restrict__ W3bT,
                                             float* __restrict__ out) {
  __shared__ unsigned short Bt[256 * 64];   // 32 KiB
  int mtile = blockIdx.x;
  int b = mtile >> 7;
  const float* Ax = x + (size_t)mtile * 128 * C_;
  const unsigned short* Bb = W3bT + (size_t)b * C_ * C_;
  int t = threadIdx.x, lane = t & 63, w = t >> 6;
  int hf = w >> 1, c2 = w & 1;
  int l8 = lane >> 3, l7 = lane & 7;
  int srcoct = l7 ^ l8;
  int l15 = lane & 15, l4 = lane >> 4;
  floatx4 acc[4][8];
  floatx4 z = {0.f, 0.f, 0.f, 0.f};
#pragma unroll
  for (int i = 0; i < 4; i++)
#pragma unroll
    for (int j = 0; j < 8; j++) acc[i][j] = z;
  for (int s = 0; s < 4; s++) {
    if (s) __syncthreads();
#pragma unroll
    for (int i = 0; i < 8; i++) {
      int ib = w * 8 + i;                  // 0..31 -> B rows 0..255
      int row = ib * 8 + l8;
      gl_lds16(Bb + (size_t)row * C_ + s * 64 + srcoct * 8, Bt + ib * 512);
    }
    __syncthreads();
#pragma unroll
    for (int kk = 0; kk < 2; kk++) {
      short8 af[4], bfv[8];
      int oct = kk * 4 + l4;
#pragma unroll
      for (int tm = 0; tm < 4; tm++) {
        int row = hf * 64 + tm * 16 + l15;
        const float* p = Ax + (size_t)row * C_ + s * 64 + oct * 8;
        float4 u0 = *(const float4*)p;
        float4 u1 = *(const float4*)(p + 4);
        short8 v;
        v[0] = (short)f2bf(u0.x); v[1] = (short)f2bf(u0.y);
        v[2] = (short)f2bf(u0.z); v[3] = (short)f2bf(u0.w);
        v[4] = (short)f2bf(u1.x); v[5] = (short)f2bf(u1.y);
        v[6] = (short)f2bf(u1.z); v[7] = (short)f2bf(u1.w);
        af[tm] = v;
      }
#pragma unroll
      for (int tn = 0; tn < 8; tn++) {
        int row = c2 * 128 + tn * 16 + l15;
        bfv[tn] = *(const short8*)(Bt + row * 64 + ((oct ^ (row & 7)) * 8));
      }
#pragma unroll
      for (int tm = 0; tm < 4; tm++)
#pragma unroll
        for (int tn = 0; tn < 8; tn++)
          acc[tm][tn] = __builtin_amdgcn_mfma_f32_16x16x32_bf16(af[tm], bfv[tn],
                                                                acc[tm][tn], 0, 0, 0);
    }
  }
  float* ob = out + (size_t)mtile * 128 * C_;
#pragma unroll
  for (int tm = 0; tm < 4; tm++)
#pragma unroll
    for (int tn = 0; tn < 8; tn++)
#pragma unroll
      for (int r = 0; r < 4; r++) {
        int m = hf * 64 + tm * 16 + l4 * 4 + r;
        int n = c2 * 128 + tn * 16 + l15;
        ob[(size_t)m * C_ + n] = acc[tm][tn][r];
      }
}

// ---------------------------------------------------------------------------
extern "C" void kernel_launch(void* const* d_in, const int* in_sizes, int n_in,
                              void* d_out, int out_size, void* d_ws, size_t ws_size,
                              hipStream_t stream) {
  const float* x    = (const float*)d_in[0];
  const float* Wq   = (const float*)d_in[1];
  const float* Wk   = (const float*)d_in[2];
  const float* Wv   = (const float*)d_in[3];
  const float* Wout = (const float*)d_in[4];
  float* out = (float*)d_out;

  // workspace carve-up (~36.5 MiB)
  float* part = (float*)d_ws;                           // 4*32*256*256 fp32 = 32 MiB
  float* S    = part + (size_t)8388608;                 // 1 MiB
  float* SWq  = S + 262144;                             // 1 MiB
  float* SWk  = SWq + 262144;                           // 1 MiB
  float* U    = SWk + 262144;                           // 1 MiB
  unsigned short* W3bT = (unsigned short*)(U + 262144); // 512 KiB

  k_sgemm<<<dim3(256), dim3(512), 0, stream>>>(x, part);
  k_sred<<<dim3(256), dim3(256), 0, stream>>>(part, S);
  k_gemm_sw<<<dim3(128), dim3(256), 0, stream>>>(S, Wq, Wk, SWq, SWk);
  k_fuse<<<dim3(32), dim3(256), 0, stream>>>(Wq, Wk, SWq, SWk, Wout, U);
  k_gemm_w3<<<dim3(64), dim3(256), 0, stream>>>(Wv, U, W3bT);
  k_out<<<dim3(512), dim3(256), 0, stream>>>(x, W3bT, out);
}

// Round 6
// 224.394 us; speedup vs baseline: 1.0058x; 1.0058x over previous
//
#include <hip/hip_runtime.h>

// SpectralMultiHeadAttention on MI355X (gfx950)
// b=4, hw=16384, c=256, heads=8, dh=32.
// Reformulation: S[b] = x^T x (256x256);  G = Wq^T S Wk;  qss = diag(Wq^T S Wq);
// kss = diag(Wk^T S Wk);  A = softmax(G_blocks / (nq nk sqrt(hw)));
// out = x @ (Wv @ Abig^T @ Wout).   q/k/v never materialized.
// R9: (a) k_sgemm reverted to R7 single-buffer (R8's 128KiB dbuf halved
//     blocks/CU -> +6us). Native cast kept. (b) k_sgemm hs==0 blocks also
//     emit bf16 xb (they hold every cast element in regs anyway) so that
//     (c) k_out stages BOTH operands via swizzled global_load_lds and runs a
//     pure ds_read_b128+MFMA inner loop -- R8's k_out exposed per-fragment
//     global latency inline (42.6us at 7% MFMA / 31% HBM / 8.9% occ).

#define B_   4
#define HW_  16384
#define C_   256

typedef __attribute__((ext_vector_type(8))) short short8;
typedef __attribute__((ext_vector_type(4))) float floatx4;

__device__ __forceinline__ unsigned short f2bf(float f) {
  return __builtin_bit_cast(unsigned short, (__bf16)f);   // v_cvt (RNE)
}

__device__ __forceinline__ void gl_lds16(const unsigned short* g, unsigned short* l) {
  __builtin_amdgcn_global_load_lds(
      (const __attribute__((address_space(1))) unsigned int*)g,
      (__attribute__((address_space(3))) unsigned int*)l, 16, 0, 0);
}

// ---------------------------------------------------------------------------
// K2: S partials. grid 256 = half(1b) | ks(5b) | b(2b), 512 thr. Each block
// stages the FULL 256c x 128hw bf16 panel (4 phases over its 512-hw chunk,
// single 64 KiB buffer, 2 blocks/CU) and computes a 128-row half of the
// 256x256 output. XOR-octet swizzle. Register prefetch of the next phase's
// globals under the current phase's MFMA. hs==0 blocks additionally store
// the cast rows to xb (row-major bf16) for k_out's DMA staging.
// K order identical to R7/R8 -> S bitwise-same.
// ---------------------------------------------------------------------------
__global__ __launch_bounds__(512) void k_sgemm(const float* __restrict__ x,
                                               float* __restrict__ part,
                                               unsigned short* __restrict__ xb) {
  __shared__ unsigned short Pt[256 * 128];   // 64 KiB
  int bid = blockIdx.x;
  int hs = bid & 1, ks = (bid >> 1) & 31, b = bid >> 6;
  const float* xv = x + ((size_t)(b * HW_ + ks * 512)) * C_;
  unsigned short* xbp = xb + ((size_t)(b * HW_ + ks * 512)) * C_;
  int t = threadIdx.x, lane = t & 63, w = t >> 6;   // 8 waves
  int rw = w >> 2, cw = w & 3;                      // 2x4 wave grid on 128x256
  int m0 = hs * 128 + rw * 64;
  int n0 = cw * 64;
  int l15 = lane & 15, l4 = lane >> 4;
  int s_cq  = (lane >> 3) | (w << 3);       // 0..63: which c-quad
  int s_hpl = lane & 7;                     // low 3 bits of hw-pair
  floatx4 acc[4][4];
  floatx4 z = {0.f, 0.f, 0.f, 0.f};
#pragma unroll
  for (int i = 0; i < 4; i++)
#pragma unroll
    for (int j = 0; j < 4; j++) acc[i][j] = z;

  // stage phase 0 (load -> cvt -> ds_write [+ xb store])
#pragma unroll
  for (int e = 0; e < 8; e++) {
    int hp = s_hpl | (e << 3);
    const float* src = xv + ((size_t)(hp * 2)) * C_ + s_cq * 4;
    float4 v0 = *(const float4*)src;
    float4 v1 = *(const float4*)(src + C_);
    float a0[4] = {v0.x, v0.y, v0.z, v0.w};
    float a1[4] = {v1.x, v1.y, v1.z, v1.w};
    if (hs == 0) {
      ushort4 h0, h1;
      h0.x = f2bf(a0[0]); h0.y = f2bf(a0[1]); h0.z = f2bf(a0[2]); h0.w = f2bf(a0[3]);
      h1.x = f2bf(a1[0]); h1.y = f2bf(a1[1]); h1.z = f2bf(a1[2]); h1.w = f2bf(a1[3]);
      *(ushort4*)(xbp + (size_t)(hp * 2) * C_ + s_cq * 4) = h0;
      *(ushort4*)(xbp + (size_t)(hp * 2 + 1) * C_ + s_cq * 4) = h1;
    }
#pragma unroll
    for (int i = 0; i < 4; i++) {
      unsigned u = (unsigned)f2bf(a0[i]) | ((unsigned)f2bf(a1[i]) << 16);
      int r = s_cq * 4 + i;
      int slot = (hp >> 2) ^ (r & 15);
      ((unsigned*)Pt)[r * 64 + slot * 4 + (hp & 3)] = u;
    }
  }
  __syncthreads();

  float4 pA[8], pB[8];
  for (int ph = 0; ph < 4; ph++) {
    if (ph < 3) {
      // issue next phase's global loads early (latency under MFMA below)
#pragma unroll
      for (int e = 0; e < 8; e++) {
        int hp = s_hpl | (e << 3);
        const float* src = xv + ((size_t)((ph + 1) * 128 + hp * 2)) * C_ + s_cq * 4;
        pA[e] = *(const float4*)src;
        pB[e] = *(const float4*)(src + C_);
      }
    }
#pragma unroll
    for (int kk = 0; kk < 4; kk++) {       // 4 k-steps of 32 per phase
      short8 af[4], bfv[4];
      int oct = kk * 4 + l4;
#pragma unroll
      for (int tm = 0; tm < 4; tm++) {
        int row = m0 + tm * 16 + l15;
        af[tm] = *(const short8*)(Pt + row * 128 + ((oct ^ (row & 15)) * 8));
      }
#pragma unroll
      for (int tn = 0; tn < 4; tn++) {
        int row = n0 + tn * 16 + l15;
        bfv[tn] = *(const short8*)(Pt + row * 128 + ((oct ^ (row & 15)) * 8));
      }
#pragma unroll
      for (int tm = 0; tm < 4; tm++)
#pragma unroll
        for (int tn = 0; tn < 4; tn++)
          acc[tm][tn] = __builtin_amdgcn_mfma_f32_16x16x32_bf16(af[tm], bfv[tn],
                                                                acc[tm][tn], 0, 0, 0);
    }
    if (ph < 3) {
      __syncthreads();                     // everyone done reading Pt(ph)
#pragma unroll
      for (int e = 0; e < 8; e++) {
        int hp = s_hpl | (e << 3);
        float a0[4] = {pA[e].x, pA[e].y, pA[e].z, pA[e].w};
        float a1[4] = {pB[e].x, pB[e].y, pB[e].z, pB[e].w};
        if (hs == 0) {
          ushort4 h0, h1;
          h0.x = f2bf(a0[0]); h0.y = f2bf(a0[1]); h0.z = f2bf(a0[2]); h0.w = f2bf(a0[3]);
          h1.x = f2bf(a1[0]); h1.y = f2bf(a1[1]); h1.z = f2bf(a1[2]); h1.w = f2bf(a1[3]);
          *(ushort4*)(xbp + (size_t)((ph + 1) * 128 + hp * 2) * C_ + s_cq * 4) = h0;
          *(ushort4*)(xbp + (size_t)((ph + 1) * 128 + hp * 2 + 1) * C_ + s_cq * 4) = h1;
        }
#pragma unroll
        for (int i = 0; i < 4; i++) {
          unsigned u = (unsigned)f2bf(a0[i]) | ((unsigned)f2bf(a1[i]) << 16);
          int r = s_cq * 4 + i;
          int slot = (hp >> 2) ^ (r & 15);
          ((unsigned*)Pt)[r * 64 + slot * 4 + (hp & 3)] = u;
        }
      }
      __syncthreads();                     // Pt(ph+1) ready
    }
  }
  // epilogue: streaming fp32 partial half-tile [b][ks][m 128-half][256]
  float* pb = part + (size_t)(b * 32 + ks) * 65536;
#pragma unroll
  for (int tm = 0; tm < 4; tm++)
#pragma unroll
    for (int tn = 0; tn < 4; tn++)
#pragma unroll
      for (int r = 0; r < 4; r++) {
        int m = m0 + tm * 16 + l4 * 4 + r;   // C/D: row=(lane>>4)*4+reg
        int n = n0 + tn * 16 + l15;          //      col=lane&15
        pb[m * 256 + n] = acc[tm][tn][r];
      }
}

// K2r: reduce 32 K-partials -> S fp32 [b][256][256]. grid 256 x 256, float4.
__global__ __launch_bounds__(256) void k_sred(const float* __restrict__ part,
                                              float* __restrict__ S) {
  int g = blockIdx.x * 256 + threadIdx.x;     // 0..65535 float4 slots
  int b = g >> 14, off = (g & 16383) * 4;
  const float* p = part + ((size_t)b << 21) + off;
  float4 s = {0.f, 0.f, 0.f, 0.f};
#pragma unroll
  for (int k = 0; k < 32; k++) {
    float4 v = *(const float4*)(p + ((size_t)k << 16));
    s.x += v.x; s.y += v.y; s.z += v.z; s.w += v.w;
  }
  *(float4*)(S + ((size_t)b << 16) + off) = s;
}

// ---------------------------------------------------------------------------
// K3a: SWq = S@Wq, SWk = S@Wk (fp32, 64x64 tiles). grid 128 = b(4)*mt(4)*nt(8).
// ---------------------------------------------------------------------------
__global__ __launch_bounds__(256) void k_gemm_sw(const float* __restrict__ S,
                                                 const float* __restrict__ Wq,
                                                 const float* __restrict__ Wk,
                                                 float* __restrict__ SWq,
                                                 float* __restrict__ SWk) {
  __shared__ float Ast[16][68];
  __shared__ float Bs[16][68];
  int bid = blockIdx.x;
  int nt = bid & 7, mt = (bid >> 3) & 3, b = bid >> 5;
  int mb = mt * 64;
  const float* Wsel = (nt < 4) ? Wq : Wk;
  int nb = (nt & 3) * 64;
  int t = threadIdx.x, tx = t & 15, ty = t >> 4;
  float acc[4][4] = {};
  for (int kt = 0; kt < 16; kt++) {
    {
      int row = t >> 2, kq = t & 3;
      float4 v = *(const float4*)(S + ((size_t)(b * C_ + mb + row)) * C_ + kt * 16 + kq * 4);
      Ast[kq * 4 + 0][row] = v.x; Ast[kq * 4 + 1][row] = v.y;
      Ast[kq * 4 + 2][row] = v.z; Ast[kq * 4 + 3][row] = v.w;
    }
    {
      int kk = t >> 4, n4 = t & 15;
      float4 v = *(const float4*)(Wsel + ((size_t)(kt * 16 + kk)) * C_ + nb + n4 * 4);
      *(float4*)&Bs[kk][n4 * 4] = v;
    }
    __syncthreads();
#pragma unroll
    for (int k = 0; k < 16; k++) {
      float4 a4 = *(const float4*)&Ast[k][ty * 4];
      float4 b4 = *(const float4*)&Bs[k][tx * 4];
      float a[4] = {a4.x, a4.y, a4.z, a4.w};
      float bb[4] = {b4.x, b4.y, b4.z, b4.w};
#pragma unroll
      for (int i = 0; i < 4; i++)
#pragma unroll
        for (int j = 0; j < 4; j++) acc[i][j] += a[i] * bb[j];
    }
    __syncthreads();
  }
#pragma unroll
  for (int i = 0; i < 4; i++)
#pragma unroll
    for (int j = 0; j < 4; j++) {
      int row = mb + ty * 4 + i;
      int ng = nt * 64 + tx * 4 + j;
      if (ng < 256) SWq[((size_t)(b * C_ + row)) * C_ + ng] = acc[i][j];
      else          SWk[((size_t)(b * C_ + row)) * C_ + ng - 256] = acc[i][j];
    }
}

// ---------------------------------------------------------------------------
// K3f: fused G_h + norms + softmax + U_h. grid 32 = (b,h), 256 thr.
// ---------------------------------------------------------------------------
__global__ __launch_bounds__(256) void k_fuse(const float* __restrict__ Wq,
                                              const float* __restrict__ Wk,
                                              const float* __restrict__ SWq,
                                              const float* __restrict__ SWk,
                                              const float* __restrict__ Wout,
                                              float* __restrict__ U) {
  __shared__ float Wqh[256][32];    // 32 KiB (reused as Wo[32][256] for U phase)
  __shared__ float Wkh[256][32];
  __shared__ float SWqh[256][32];
  __shared__ float SWkh[256][32];   // total 128 KiB
  __shared__ float Lg[32][33];
  __shared__ float qp[8][32], kp[8][32], qin[32], kin[32];
  int b = blockIdx.x >> 3, h = blockIdx.x & 7;
  int t = threadIdx.x;
  int col = t & 31, rgrp = t >> 5;               // 8 rows per sweep
  for (int r0 = 0; r0 < 256; r0 += 8) {
    int row = r0 + rgrp;
    Wqh[row][col]  = Wq[(size_t)row * C_ + h * 32 + col];
    Wkh[row][col]  = Wk[(size_t)row * C_ + h * 32 + col];
    SWqh[row][col] = SWq[((size_t)(b * C_ + row)) * C_ + h * 32 + col];
    SWkh[row][col] = SWk[((size_t)(b * C_ + row)) * C_ + h * 32 + col];
  }
  __syncthreads();
  {
    float g[4] = {0.f, 0.f, 0.f, 0.f};
    for (int k = 0; k < 256; k++) {
      float swk = SWkh[k][col];
#pragma unroll
      for (int r = 0; r < 4; r++) g[r] += Wqh[k][rgrp + 8 * r] * swk;
    }
#pragma unroll
    for (int r = 0; r < 4; r++) Lg[rgrp + 8 * r][col] = g[r];
  }
  {
    float sq = 0.f, sk = 0.f;
    for (int k = rgrp * 32; k < rgrp * 32 + 32; k++) {
      sq += Wqh[k][col] * SWqh[k][col];
      sk += Wkh[k][col] * SWkh[k][col];
    }
    qp[rgrp][col] = sq;
    kp[rgrp][col] = sk;
  }
  __syncthreads();
  if (t < 32) {
    float a = 0.f;
#pragma unroll
    for (int p = 0; p < 8; p++) a += qp[p][t];
    qin[t] = rsqrtf(a);
  } else if (t < 64) {
    int j = t - 32;
    float a = 0.f;
#pragma unroll
    for (int p = 0; p < 8; p++) a += kp[p][j];
    kin[j] = rsqrtf(a);
  }
  __syncthreads();
  if (t < 32) {
    float row[32];
    float mx = -1e30f;
#pragma unroll
    for (int j = 0; j < 32; j++) {
      row[j] = Lg[t][j] * qin[t] * kin[j] * 0.0078125f;   // /sqrt(16384)
      mx = fmaxf(mx, row[j]);
    }
    float sum = 0.f;
#pragma unroll
    for (int j = 0; j < 32; j++) { row[j] = __expf(row[j] - mx); sum += row[j]; }
    float inv = 1.0f / sum;
#pragma unroll
    for (int j = 0; j < 32; j++) Lg[t][j] = row[j] * inv;
  }
  __syncthreads();
  float (*Wo)[256] = reinterpret_cast<float(*)[256]>(&Wqh[0][0]);
#pragma unroll
  for (int r = 0; r < 32; r++) Wo[r][t] = Wout[((size_t)(h * 32 + r)) * C_ + t];
  __syncthreads();
  for (int j = 0; j < 32; j++) {
    float a = 0.f;
#pragma unroll
    for (int i2 = 0; i2 < 32; i2++) a += Lg[i2][j] * Wo[i2][t];
    U[((size_t)(b * C_ + h * 32 + j)) * C_ + t] = a;
  }
}

// ---------------------------------------------------------------------------
// K3e: W3 = Wv @ U[b], emitted transposed bf16: W3bT[b][n][c]. grid 64.
// ---------------------------------------------------------------------------
__global__ __launch_bounds__(256) void k_gemm_w3(const float* __restrict__ Wv,
                                                 const float* __restrict__ U,
                                                 unsigned short* __restrict__ W3bT) {
  __shared__ float Ast[16][68];
  __shared__ float Bs[16][68];
  int bid = blockIdx.x;
  int nt = bid & 3, mt = (bid >> 2) & 3, b = bid >> 4;
  int mb = mt * 64, nb = nt * 64;
  int t = threadIdx.x, tx = t & 15, ty = t >> 4;
  float acc[4][4] = {};
  for (int kt = 0; kt < 16; kt++) {
    {
      int row = t >> 2, kq = t & 3;
      float4 v = *(const float4*)(Wv + ((size_t)(mb + row)) * C_ + kt * 16 + kq * 4);
      Ast[kq * 4 + 0][row] = v.x; Ast[kq * 4 + 1][row] = v.y;
      Ast[kq * 4 + 2][row] = v.z; Ast[kq * 4 + 3][row] = v.w;
    }
    {
      int kk = t >> 4, n4 = t & 15;
      float4 v = *(const float4*)(U + ((size_t)(b * C_ + kt * 16 + kk)) * C_ + nb + n4 * 4);
      *(float4*)&Bs[kk][n4 * 4] = v;
    }
    __syncthreads();
#pragma unroll
    for (int k = 0; k < 16; k++) {
      float4 a4 = *(const float4*)&Ast[k][ty * 4];
      float4 b4 = *(const float4*)&Bs[k][tx * 4];
      float a[4] = {a4.x, a4.y, a4.z, a4.w};
      float bb[4] = {b4.x, b4.y, b4.z, b4.w};
#pragma unroll
      for (int i = 0; i < 4; i++)
#pragma unroll
        for (int j = 0; j < 4; j++) acc[i][j] += a[i] * bb[j];
    }
    __syncthreads();
  }
#pragma unroll
  for (int i = 0; i < 4; i++)
#pragma unroll
    for (int j = 0; j < 4; j++)
      W3bT[((size_t)(b * C_ + nb + tx * 4 + j)) * C_ + mb + ty * 4 + i] = f2bf(acc[i][j]);
}

// ---------------------------------------------------------------------------
// K4: out = xb @ W3[b], fp32 out. grid 512 = mtile, BN=256 per block.
// BOTH operands staged via swizzled global_load_lds (8-slot XOR rows);
// inner loop is pure ds_read_b128 + MFMA. BK=64, 4 stages. LDS 48 KiB.
// ---------------------------------------------------------------------------
__global__ __launch_bounds__(256) void k_out(const unsigned short* __restrict__ xb,
                                             const unsigned short* __restrict__ W3bT,
                                             float* __restrict__ out) {
  __shared__ unsigned short At[128 * 64];   // 16 KiB
  __shared__ unsigned short Bt[256 * 64];   // 32 KiB
  int mtile = blockIdx.x;
  int b = mtile >> 7;
  const unsigned short* Ab = xb + (size_t)mtile * 128 * C_;
  const unsigned short* Bb = W3bT + (size_t)b * C_ * C_;
  int t = threadIdx.x, lane = t & 63, w = t >> 6;
  int hf = w >> 1, c2 = w & 1;
  int l8 = lane >> 3, l7 = lane & 7;
  int srcoct = l7 ^ l8;
  int l15 = lane & 15, l4 = lane >> 4;
  floatx4 acc[4][8];
  floatx4 z = {0.f, 0.f, 0.f, 0.f};
#pragma unroll
  for (int i = 0; i < 4; i++)
#pragma unroll
    for (int j = 0; j < 8; j++) acc[i][j] = z;
  for (int s = 0; s < 4; s++) {
    if (s) __syncthreads();
#pragma unroll
    for (int i = 0; i < 4; i++) {
      int ia = w * 4 + i;                  // 0..15 -> A rows 0..127
      int row = ia * 8 + l8;
      gl_lds16(Ab + (size_t)row * C_ + s * 64 + srcoct * 8, At + ia * 512);
    }
#pragma unroll
    for (int i = 0; i < 8; i++) {
      int ib = w * 8 + i;                  // 0..31 -> B rows 0..255
      int row = ib * 8 + l8;
      gl_lds16(Bb + (size_t)row * C_ + s * 64 + srcoct * 8, Bt + ib * 512);
    }
    __syncthreads();
#pragma unroll
    for (int kk = 0; kk < 2; kk++) {
      short8 af[4], bfv[8];
      int oct = kk * 4 + l4;
#pragma unroll
      for (int tm = 0; tm < 4; tm++) {
        int row = hf * 64 + tm * 16 + l15;
        af[tm] = *(const short8*)(At + row * 64 + ((oct ^ (row & 7)) * 8));
      }
#pragma unroll
      for (int tn = 0; tn < 8; tn++) {
        int row = c2 * 128 + tn * 16 + l15;
        bfv[tn] = *(const short8*)(Bt + row * 64 + ((oct ^ (row & 7)) * 8));
      }
#pragma unroll
      for (int tm = 0; tm < 4; tm++)
#pragma unroll
        for (int tn = 0; tn < 8; tn++)
          acc[tm][tn] = __builtin_amdgcn_mfma_f32_16x16x32_bf16(af[tm], bfv[tn],
                                                                acc[tm][tn], 0, 0, 0);
    }
  }
  float* ob = out + (size_t)mtile * 128 * C_;
#pragma unroll
  for (int tm = 0; tm < 4; tm++)
#pragma unroll
    for (int tn = 0; tn < 8; tn++)
#pragma unroll
      for (int r = 0; r < 4; r++) {
        int m = hf * 64 + tm * 16 + l4 * 4 + r;
        int n = c2 * 128 + tn * 16 + l15;
        ob[(size_t)m * C_ + n] = acc[tm][tn][r];
      }
}

// ---------------------------------------------------------------------------
extern "C" void kernel_launch(void* const* d_in, const int* in_sizes, int n_in,
                              void* d_out, int out_size, void* d_ws, size_t ws_size,
                              hipStream_t stream) {
  const float* x    = (const float*)d_in[0];
  const float* Wq   = (const float*)d_in[1];
  const float* Wk   = (const float*)d_in[2];
  const float* Wv   = (const float*)d_in[3];
  const float* Wout = (const float*)d_in[4];
  float* out = (float*)d_out;

  // workspace carve-up (~68.5 MiB)
  float* part = (float*)d_ws;                           // 4*32*256*256 fp32 = 32 MiB
  float* S    = part + (size_t)8388608;                 // 1 MiB
  float* SWq  = S + 262144;                             // 1 MiB
  float* SWk  = SWq + 262144;                           // 1 MiB
  float* U    = SWk + 262144;                           // 1 MiB
  unsigned short* W3bT = (unsigned short*)(U + 262144); // 512 KiB
  unsigned short* xb   = W3bT + (size_t)262144;         // 32 MiB bf16 x

  k_sgemm<<<dim3(256), dim3(512), 0, stream>>>(x, part, xb);
  k_sred<<<dim3(256), dim3(256), 0, stream>>>(part, S);
  k_gemm_sw<<<dim3(128), dim3(256), 0, stream>>>(S, Wq, Wk, SWq, SWk);
  k_fuse<<<dim3(32), dim3(256), 0, stream>>>(Wq, Wk, SWq, SWk, Wout, U);
  k_gemm_w3<<<dim3(64), dim3(256), 0, stream>>>(Wv, U, W3bT);
  k_out<<<dim3(512), dim3(256), 0, stream>>>(xb, W3bT, out);
}

// Round 7
// 219.237 us; speedup vs baseline: 1.0295x; 1.0235x over previous
//
#include <hip/hip_runtime.h>

// SpectralMultiHeadAttention on MI355X (gfx950)
// b=4, hw=16384, c=256, heads=8, dh=32.
// Reformulation: S[b] = x^T x (256x256);  G = Wq^T S Wk;  qss = diag(Wq^T S Wq);
// kss = diag(Wk^T S Wk);  A = softmax(G_blocks / (nq nk sqrt(hw)));
// out = x @ (Wv @ Abig^T @ Wout).   q/k/v never materialized.
// R10: (a) xb dropped (R9: producer-side stores cost 6us in the latency-bound
//     producer). (b) k_sgemm hs-pairs XCD-co-located via bid remap
//     (chunk=(bid&7)|((bid>>4)<<3), hs=(bid>>3)&1): R9 showed consecutive-bid
//     pairs land on different XCDs -> x fetched twice from HBM (FETCH 65.6MB).
//     Same-XCD pairs turn the 2nd read into L2 hits. (c) k_out stages A as
//     fp32 via global_load_lds (16B-unit XOR swizzle, 2-way banks) + register
//     cvt -> no exposed inline global latency (R8's 42.6us failure mode),
//     no xb materialization needed.

#define B_   4
#define HW_  16384
#define C_   256

typedef __attribute__((ext_vector_type(8))) short short8;
typedef __attribute__((ext_vector_type(4))) float floatx4;

__device__ __forceinline__ unsigned short f2bf(float f) {
  return __builtin_bit_cast(unsigned short, (__bf16)f);   // v_cvt (RNE)
}

__device__ __forceinline__ void gl_lds16(const unsigned short* g, unsigned short* l) {
  __builtin_amdgcn_global_load_lds(
      (const __attribute__((address_space(1))) unsigned int*)g,
      (__attribute__((address_space(3))) unsigned int*)l, 16, 0, 0);
}

__device__ __forceinline__ void gl_lds16f(const float* g, float* l) {
  __builtin_amdgcn_global_load_lds(
      (const __attribute__((address_space(1))) unsigned int*)g,
      (__attribute__((address_space(3))) unsigned int*)l, 16, 0, 0);
}

// ---------------------------------------------------------------------------
// K2: S partials. grid 256, 512 thr. bid remap: chunk=(bid&7)|((bid>>4)<<3)
// (= b(2b)<<5 | ks(5b)), hs=(bid>>3)&1 -> the two blocks of a chunk are 8
// bids apart -> same XCD (round-robin dispatch) -> shared-chunk L2 hits.
// Each block stages the FULL 256c x 128hw bf16 panel (4 phases over its
// 512-hw chunk, single 64 KiB buffer, 2 blocks/CU) and computes a 128-row
// half of the 256x256 output. XOR-octet swizzle. Register prefetch of the
// next phase's globals under the current phase's MFMA.
// K order identical to R7 -> S bitwise-same.
// ---------------------------------------------------------------------------
__global__ __launch_bounds__(512) void k_sgemm(const float* __restrict__ x,
                                               float* __restrict__ part) {
  __shared__ unsigned short Pt[256 * 128];   // 64 KiB
  int bid = blockIdx.x;
  int chunkid = (bid & 7) | ((bid >> 4) << 3);   // 0..127
  int hs = (bid >> 3) & 1;
  int ks = chunkid & 31, b = chunkid >> 5;
  const float* xv = x + ((size_t)(b * HW_ + ks * 512)) * C_;
  int t = threadIdx.x, lane = t & 63, w = t >> 6;   // 8 waves
  int rw = w >> 2, cw = w & 3;                      // 2x4 wave grid on 128x256
  int m0 = hs * 128 + rw * 64;
  int n0 = cw * 64;
  int l15 = lane & 15, l4 = lane >> 4;
  int s_cq  = (lane >> 3) | (w << 3);       // 0..63: which c-quad
  int s_hpl = lane & 7;                     // low 3 bits of hw-pair
  floatx4 acc[4][4];
  floatx4 z = {0.f, 0.f, 0.f, 0.f};
#pragma unroll
  for (int i = 0; i < 4; i++)
#pragma unroll
    for (int j = 0; j < 4; j++) acc[i][j] = z;

  // stage phase 0 (load -> cvt -> ds_write)
#pragma unroll
  for (int e = 0; e < 8; e++) {
    int hp = s_hpl | (e << 3);
    const float* src = xv + ((size_t)(hp * 2)) * C_ + s_cq * 4;
    float4 v0 = *(const float4*)src;
    float4 v1 = *(const float4*)(src + C_);
    float a0[4] = {v0.x, v0.y, v0.z, v0.w};
    float a1[4] = {v1.x, v1.y, v1.z, v1.w};
#pragma unroll
    for (int i = 0; i < 4; i++) {
      unsigned u = (unsigned)f2bf(a0[i]) | ((unsigned)f2bf(a1[i]) << 16);
      int r = s_cq * 4 + i;
      int slot = (hp >> 2) ^ (r & 15);
      ((unsigned*)Pt)[r * 64 + slot * 4 + (hp & 3)] = u;
    }
  }
  __syncthreads();

  float4 pA[8], pB[8];
  for (int ph = 0; ph < 4; ph++) {
    if (ph < 3) {
      // issue next phase's global loads early (latency under MFMA below)
#pragma unroll
      for (int e = 0; e < 8; e++) {
        int hp = s_hpl | (e << 3);
        const float* src = xv + ((size_t)((ph + 1) * 128 + hp * 2)) * C_ + s_cq * 4;
        pA[e] = *(const float4*)src;
        pB[e] = *(const float4*)(src + C_);
      }
    }
#pragma unroll
    for (int kk = 0; kk < 4; kk++) {       // 4 k-steps of 32 per phase
      short8 af[4], bfv[4];
      int oct = kk * 4 + l4;
#pragma unroll
      for (int tm = 0; tm < 4; tm++) {
        int row = m0 + tm * 16 + l15;
        af[tm] = *(const short8*)(Pt + row * 128 + ((oct ^ (row & 15)) * 8));
      }
#pragma unroll
      for (int tn = 0; tn < 4; tn++) {
        int row = n0 + tn * 16 + l15;
        bfv[tn] = *(const short8*)(Pt + row * 128 + ((oct ^ (row & 15)) * 8));
      }
#pragma unroll
      for (int tm = 0; tm < 4; tm++)
#pragma unroll
        for (int tn = 0; tn < 4; tn++)
          acc[tm][tn] = __builtin_amdgcn_mfma_f32_16x16x32_bf16(af[tm], bfv[tn],
                                                                acc[tm][tn], 0, 0, 0);
    }
    if (ph < 3) {
      __syncthreads();                     // everyone done reading Pt(ph)
#pragma unroll
      for (int e = 0; e < 8; e++) {
        int hp = s_hpl | (e << 3);
        float a0[4] = {pA[e].x, pA[e].y, pA[e].z, pA[e].w};
        float a1[4] = {pB[e].x, pB[e].y, pB[e].z, pB[e].w};
#pragma unroll
        for (int i = 0; i < 4; i++) {
          unsigned u = (unsigned)f2bf(a0[i]) | ((unsigned)f2bf(a1[i]) << 16);
          int r = s_cq * 4 + i;
          int slot = (hp >> 2) ^ (r & 15);
          ((unsigned*)Pt)[r * 64 + slot * 4 + (hp & 3)] = u;
        }
      }
      __syncthreads();                     // Pt(ph+1) ready
    }
  }
  // epilogue: streaming fp32 partial half-tile [b][ks][m 128-half][256]
  float* pb = part + (size_t)(b * 32 + ks) * 65536;
#pragma unroll
  for (int tm = 0; tm < 4; tm++)
#pragma unroll
    for (int tn = 0; tn < 4; tn++)
#pragma unroll
      for (int r = 0; r < 4; r++) {
        int m = m0 + tm * 16 + l4 * 4 + r;   // C/D: row=(lane>>4)*4+reg
        int n = n0 + tn * 16 + l15;          //      col=lane&15
        pb[m * 256 + n] = acc[tm][tn][r];
      }
}

// K2r: reduce 32 K-partials -> S fp32 [b][256][256]. grid 256 x 256, float4.
__global__ __launch_bounds__(256) void k_sred(const float* __restrict__ part,
                                              float* __restrict__ S) {
  int g = blockIdx.x * 256 + threadIdx.x;     // 0..65535 float4 slots
  int b = g >> 14, off = (g & 16383) * 4;
  const float* p = part + ((size_t)b << 21) + off;
  float4 s = {0.f, 0.f, 0.f, 0.f};
#pragma unroll
  for (int k = 0; k < 32; k++) {
    float4 v = *(const float4*)(p + ((size_t)k << 16));
    s.x += v.x; s.y += v.y; s.z += v.z; s.w += v.w;
  }
  *(float4*)(S + ((size_t)b << 16) + off) = s;
}

// ---------------------------------------------------------------------------
// K3a: SWq = S@Wq, SWk = S@Wk (fp32, 64x64 tiles). grid 128 = b(4)*mt(4)*nt(8).
// ---------------------------------------------------------------------------
__global__ __launch_bounds__(256) void k_gemm_sw(const float* __restrict__ S,
                                                 const float* __restrict__ Wq,
                                                 const float* __restrict__ Wk,
                                                 float* __restrict__ SWq,
                                                 float* __restrict__ SWk) {
  __shared__ float Ast[16][68];
  __shared__ float Bs[16][68];
  int bid = blockIdx.x;
  int nt = bid & 7, mt = (bid >> 3) & 3, b = bid >> 5;
  int mb = mt * 64;
  const float* Wsel = (nt < 4) ? Wq : Wk;
  int nb = (nt & 3) * 64;
  int t = threadIdx.x, tx = t & 15, ty = t >> 4;
  float acc[4][4] = {};
  for (int kt = 0; kt < 16; kt++) {
    {
      int row = t >> 2, kq = t & 3;
      float4 v = *(const float4*)(S + ((size_t)(b * C_ + mb + row)) * C_ + kt * 16 + kq * 4);
      Ast[kq * 4 + 0][row] = v.x; Ast[kq * 4 + 1][row] = v.y;
      Ast[kq * 4 + 2][row] = v.z; Ast[kq * 4 + 3][row] = v.w;
    }
    {
      int kk = t >> 4, n4 = t & 15;
      float4 v = *(const float4*)(Wsel + ((size_t)(kt * 16 + kk)) * C_ + nb + n4 * 4);
      *(float4*)&Bs[kk][n4 * 4] = v;
    }
    __syncthreads();
#pragma unroll
    for (int k = 0; k < 16; k++) {
      float4 a4 = *(const float4*)&Ast[k][ty * 4];
      float4 b4 = *(const float4*)&Bs[k][tx * 4];
      float a[4] = {a4.x, a4.y, a4.z, a4.w};
      float bb[4] = {b4.x, b4.y, b4.z, b4.w};
#pragma unroll
      for (int i = 0; i < 4; i++)
#pragma unroll
        for (int j = 0; j < 4; j++) acc[i][j] += a[i] * bb[j];
    }
    __syncthreads();
  }
#pragma unroll
  for (int i = 0; i < 4; i++)
#pragma unroll
    for (int j = 0; j < 4; j++) {
      int row = mb + ty * 4 + i;
      int ng = nt * 64 + tx * 4 + j;
      if (ng < 256) SWq[((size_t)(b * C_ + row)) * C_ + ng] = acc[i][j];
      else          SWk[((size_t)(b * C_ + row)) * C_ + ng - 256] = acc[i][j];
    }
}

// ---------------------------------------------------------------------------
// K3f: fused G_h + norms + softmax + U_h. grid 32 = (b,h), 256 thr.
// ---------------------------------------------------------------------------
__global__ __launch_bounds__(256) void k_fuse(const float* __restrict__ Wq,
                                              const float* __restrict__ Wk,
                                              const float* __restrict__ SWq,
                                              const float* __restrict__ SWk,
                                              const float* __restrict__ Wout,
                                              float* __restrict__ U) {
  __shared__ float Wqh[256][32];    // 32 KiB (reused as Wo[32][256] for U phase)
  __shared__ float Wkh[256][32];
  __shared__ float SWqh[256][32];
  __shared__ float SWkh[256][32];   // total 128 KiB
  __shared__ float Lg[32][33];
  __shared__ float qp[8][32], kp[8][32], qin[32], kin[32];
  int b = blockIdx.x >> 3, h = blockIdx.x & 7;
  int t = threadIdx.x;
  int col = t & 31, rgrp = t >> 5;               // 8 rows per sweep
  for (int r0 = 0; r0 < 256; r0 += 8) {
    int row = r0 + rgrp;
    Wqh[row][col]  = Wq[(size_t)row * C_ + h * 32 + col];
    Wkh[row][col]  = Wk[(size_t)row * C_ + h * 32 + col];
    SWqh[row][col] = SWq[((size_t)(b * C_ + row)) * C_ + h * 32 + col];
    SWkh[row][col] = SWk[((size_t)(b * C_ + row)) * C_ + h * 32 + col];
  }
  __syncthreads();
  {
    float g[4] = {0.f, 0.f, 0.f, 0.f};
    for (int k = 0; k < 256; k++) {
      float swk = SWkh[k][col];
#pragma unroll
      for (int r = 0; r < 4; r++) g[r] += Wqh[k][rgrp + 8 * r] * swk;
    }
#pragma unroll
    for (int r = 0; r < 4; r++) Lg[rgrp + 8 * r][col] = g[r];
  }
  {
    float sq = 0.f, sk = 0.f;
    for (int k = rgrp * 32; k < rgrp * 32 + 32; k++) {
      sq += Wqh[k][col] * SWqh[k][col];
      sk += Wkh[k][col] * SWkh[k][col];
    }
    qp[rgrp][col] = sq;
    kp[rgrp][col] = sk;
  }
  __syncthreads();
  if (t < 32) {
    float a = 0.f;
#pragma unroll
    for (int p = 0; p < 8; p++) a += qp[p][t];
    qin[t] = rsqrtf(a);
  } else if (t < 64) {
    int j = t - 32;
    float a = 0.f;
#pragma unroll
    for (int p = 0; p < 8; p++) a += kp[p][j];
    kin[j] = rsqrtf(a);
  }
  __syncthreads();
  if (t < 32) {
    float row[32];
    float mx = -1e30f;
#pragma unroll
    for (int j = 0; j < 32; j++) {
      row[j] = Lg[t][j] * qin[t] * kin[j] * 0.0078125f;   // /sqrt(16384)
      mx = fmaxf(mx, row[j]);
    }
    float sum = 0.f;
#pragma unroll
    for (int j = 0; j < 32; j++) { row[j] = __expf(row[j] - mx); sum += row[j]; }
    float inv = 1.0f / sum;
#pragma unroll
    for (int j = 0; j < 32; j++) Lg[t][j] = row[j] * inv;
  }
  __syncthreads();
  float (*Wo)[256] = reinterpret_cast<float(*)[256]>(&Wqh[0][0]);
#pragma unroll
  for (int r = 0; r < 32; r++) Wo[r][t] = Wout[((size_t)(h * 32 + r)) * C_ + t];
  __syncthreads();
  for (int j = 0; j < 32; j++) {
    float a = 0.f;
#pragma unroll
    for (int i2 = 0; i2 < 32; i2++) a += Lg[i2][j] * Wo[i2][t];
    U[((size_t)(b * C_ + h * 32 + j)) * C_ + t] = a;
  }
}

// ---------------------------------------------------------------------------
// K3e: W3 = Wv @ U[b], emitted transposed bf16: W3bT[b][n][c]. grid 64.
// ---------------------------------------------------------------------------
__global__ __launch_bounds__(256) void k_gemm_w3(const float* __restrict__ Wv,
                                                 const float* __restrict__ U,
                                                 unsigned short* __restrict__ W3bT) {
  __shared__ float Ast[16][68];
  __shared__ float Bs[16][68];
  int bid = blockIdx.x;
  int nt = bid & 3, mt = (bid >> 2) & 3, b = bid >> 4;
  int mb = mt * 64, nb = nt * 64;
  int t = threadIdx.x, tx = t & 15, ty = t >> 4;
  float acc[4][4] = {};
  for (int kt = 0; kt < 16; kt++) {
    {
      int row = t >> 2, kq = t & 3;
      float4 v = *(const float4*)(Wv + ((size_t)(mb + row)) * C_ + kt * 16 + kq * 4);
      Ast[kq * 4 + 0][row] = v.x; Ast[kq * 4 + 1][row] = v.y;
      Ast[kq * 4 + 2][row] = v.z; Ast[kq * 4 + 3][row] = v.w;
    }
    {
      int kk = t >> 4, n4 = t & 15;
      float4 v = *(const float4*)(U + ((size_t)(b * C_ + kt * 16 + kk)) * C_ + nb + n4 * 4);
      *(float4*)&Bs[kk][n4 * 4] = v;
    }
    __syncthreads();
#pragma unroll
    for (int k = 0; k < 16; k++) {
      float4 a4 = *(const float4*)&Ast[k][ty * 4];
      float4 b4 = *(const float4*)&Bs[k][tx * 4];
      float a[4] = {a4.x, a4.y, a4.z, a4.w};
      float bb[4] = {b4.x, b4.y, b4.z, b4.w};
#pragma unroll
      for (int i = 0; i < 4; i++)
#pragma unroll
        for (int j = 0; j < 4; j++) acc[i][j] += a[i] * bb[j];
    }
    __syncthreads();
  }
#pragma unroll
  for (int i = 0; i < 4; i++)
#pragma unroll
    for (int j = 0; j < 4; j++)
      W3bT[((size_t)(b * C_ + nb + tx * 4 + j)) * C_ + mb + ty * 4 + i] = f2bf(acc[i][j]);
}

// ---------------------------------------------------------------------------
// K4: out = x @ W3[b], fp32 out. grid 512 = mtile, BN=256 per block.
// A staged as FP32 via global_load_lds into a 16B-unit XOR-swizzled tile
// (unit u of row r at slot u^(r&15); rows are 256B so banks cycle -> 2-way);
// fragments read as 2x ds_read_b128 + v_cvt to bf16. B staged bf16 as before.
// No exposed inline global latency. LDS 64 KiB -> 2 blocks/CU.
// ---------------------------------------------------------------------------
__global__ __launch_bounds__(256) void k_out(const float* __restrict__ x,
                                             const unsigned short* __restrict__ W3bT,
                                             float* __restrict__ out) {
  __shared__ float Atf[128 * 64];           // 32 KiB fp32 A tile (swizzled)
  __shared__ unsigned short Bt[256 * 64];   // 32 KiB bf16 B tile (swizzled)
  int mtile = blockIdx.x;
  int b = mtile >> 7;
  const float* Ax = x + (size_t)mtile * 128 * C_;
  const unsigned short* Bb = W3bT + (size_t)b * C_ * C_;
  int t = threadIdx.x, lane = t & 63, w = t >> 6;
  int hf = w >> 1, c2 = w & 1;
  int l8 = lane >> 3, l7 = lane & 7;
  int srcoct = l7 ^ l8;
  int l15 = lane & 15, l4 = lane >> 4;
  int ar_l = lane >> 4;            // A staging: row sub-index 0..3
  int aslot = lane & 15;           // A staging: 16B slot within row
  floatx4 acc[4][8];
  floatx4 z = {0.f, 0.f, 0.f, 0.f};
#pragma unroll
  for (int i = 0; i < 4; i++)
#pragma unroll
    for (int j = 0; j < 8; j++) acc[i][j] = z;
  for (int s = 0; s < 4; s++) {
    if (s) __syncthreads();
    // A: 32 issues (8/wave); issue j covers rows j*4..j*4+3, 16 slots each.
    // lane dest = linear; source unit usrc = slot ^ (row&15) pre-swizzles.
#pragma unroll
    for (int i = 0; i < 8; i++) {
      int j = w * 8 + i;                   // 0..31
      int row = j * 4 + ar_l;              // 0..127
      int usrc = aslot ^ (row & 15);
      gl_lds16f(Ax + (size_t)row * C_ + s * 64 + usrc * 4, Atf + j * 256);
    }
    // B: 32 issues (8/wave), bf16 octet swizzle as before
#pragma unroll
    for (int i = 0; i < 8; i++) {
      int ib = w * 8 + i;                  // 0..31 -> B rows 0..255
      int row = ib * 8 + l8;
      gl_lds16(Bb + (size_t)row * C_ + s * 64 + srcoct * 8, Bt + ib * 512);
    }
    __syncthreads();
#pragma unroll
    for (int kk = 0; kk < 2; kk++) {
      short8 af[4], bfv[8];
      int oct = kk * 4 + l4;
#pragma unroll
      for (int tm = 0; tm < 4; tm++) {
        int row = hf * 64 + tm * 16 + l15;
        int u0 = (oct * 2) ^ (row & 15);       // slot of 1st 4-float unit
        int u1 = (oct * 2 + 1) ^ (row & 15);   // slot of 2nd
        float4 f0 = *(const float4*)(Atf + row * 64 + u0 * 4);
        float4 f1 = *(const float4*)(Atf + row * 64 + u1 * 4);
        short8 v;
        v[0] = (short)f2bf(f0.x); v[1] = (short)f2bf(f0.y);
        v[2] = (short)f2bf(f0.z); v[3] = (short)f2bf(f0.w);
        v[4] = (short)f2bf(f1.x); v[5] = (short)f2bf(f1.y);
        v[6] = (short)f2bf(f1.z); v[7] = (short)f2bf(f1.w);
        af[tm] = v;
      }
#pragma unroll
      for (int tn = 0; tn < 8; tn++) {
        int row = c2 * 128 + tn * 16 + l15;
        bfv[tn] = *(const short8*)(Bt + row * 64 + ((oct ^ (row & 7)) * 8));
      }
#pragma unroll
      for (int tm = 0; tm < 4; tm++)
#pragma unroll
        for (int tn = 0; tn < 8; tn++)
          acc[tm][tn] = __builtin_amdgcn_mfma_f32_16x16x32_bf16(af[tm], bfv[tn],
                                                                acc[tm][tn], 0, 0, 0);
    }
  }
  float* ob = out + (size_t)mtile * 128 * C_;
#pragma unroll
  for (int tm = 0; tm < 4; tm++)
#pragma unroll
    for (int tn = 0; tn < 8; tn++)
#pragma unroll
      for (int r = 0; r < 4; r++) {
        int m = hf * 64 + tm * 16 + l4 * 4 + r;
        int n = c2 * 128 + tn * 16 + l15;
        ob[(size_t)m * C_ + n] = acc[tm][tn][r];
      }
}

// ---------------------------------------------------------------------------
extern "C" void kernel_launch(void* const* d_in, const int* in_sizes, int n_in,
                              void* d_out, int out_size, void* d_ws, size_t ws_size,
                              hipStream_t stream) {
  const float* x    = (const float*)d_in[0];
  const float* Wq   = (const float*)d_in[1];
  const float* Wk   = (const float*)d_in[2];
  const float* Wv   = (const float*)d_in[3];
  const float* Wout = (const float*)d_in[4];
  float* out = (float*)d_out;

  // workspace carve-up (~36.5 MiB)
  float* part = (float*)d_ws;                           // 4*32*256*256 fp32 = 32 MiB
  float* S    = part + (size_t)8388608;                 // 1 MiB
  float* SWq  = S + 262144;                             // 1 MiB
  float* SWk  = SWq + 262144;                           // 1 MiB
  float* U    = SWk + 262144;                           // 1 MiB
  unsigned short* W3bT = (unsigned short*)(U + 262144); // 512 KiB

  k_sgemm<<<dim3(256), dim3(512), 0, stream>>>(x, part);
  k_sred<<<dim3(256), dim3(256), 0, stream>>>(part, S);
  k_gemm_sw<<<dim3(128), dim3(256), 0, stream>>>(S, Wq, Wk, SWq, SWk);
  k_fuse<<<dim3(32), dim3(256), 0, stream>>>(Wq, Wk, SWq, SWk, Wout, U);
  k_gemm_w3<<<dim3(64), dim3(256), 0, stream>>>(Wv, U, W3bT);
  k_out<<<dim3(512), dim3(256), 0, stream>>>(x, W3bT, out);
}

// Round 8
// 214.260 us; speedup vs baseline: 1.0534x; 1.0232x over previous
//
#include <hip/hip_runtime.h>

// SpectralMultiHeadAttention on MI355X (gfx950)
// b=4, hw=16384, c=256, heads=8, dh=32.
// Reformulation: S[b] = x^T x (256x256);  G = Wq^T S Wk;  qss = diag(Wq^T S Wq);
// kss = diag(Wk^T S Wk);  A = softmax(G_blocks / (nq nk sqrt(hw)));
// out = x @ (Wv @ Abig^T @ Wout).   q/k/v never materialized.
// R11: k_out occupancy fix. R8 counters: 103 MB HBM at 2.47 TB/s, occ 8.9%
//     -> Little's-law-bound (too few blocks/waves in flight). New shape:
//     BN=128, BK=32, LDS 24 KiB (Atf fp32 16K + Bt bf16 8K), acc[4][4]
//     -> 4 blocks/CU, 16 waves/CU. Both operands via swizzled
//     global_load_lds; ntile pairs XCD-co-located so the shared A-panel
//     is an L2 hit. Same K-chain per output -> bitwise-identical.
//     k_sgemm left as R10 (VGPR-capped at the 16-wave class; its 2.9 TB/s
//     is the prefetch-register Little's-law ceiling).

#define B_   4
#define HW_  16384
#define C_   256

typedef __attribute__((ext_vector_type(8))) short short8;
typedef __attribute__((ext_vector_type(4))) float floatx4;

__device__ __forceinline__ unsigned short f2bf(float f) {
  return __builtin_bit_cast(unsigned short, (__bf16)f);   // v_cvt (RNE)
}

__device__ __forceinline__ void gl_lds16(const unsigned short* g, unsigned short* l) {
  __builtin_amdgcn_global_load_lds(
      (const __attribute__((address_space(1))) unsigned int*)g,
      (__attribute__((address_space(3))) unsigned int*)l, 16, 0, 0);
}

__device__ __forceinline__ void gl_lds16f(const float* g, float* l) {
  __builtin_amdgcn_global_load_lds(
      (const __attribute__((address_space(1))) unsigned int*)g,
      (__attribute__((address_space(3))) unsigned int*)l, 16, 0, 0);
}

// ---------------------------------------------------------------------------
// K2: S partials. grid 256, 512 thr. bid remap: chunk=(bid&7)|((bid>>4)<<3),
// hs=(bid>>3)&1 -> the two blocks of a chunk are 8 bids apart -> same XCD ->
// shared-chunk L2 hits. Each block stages the FULL 256c x 128hw bf16 panel
// (4 phases over its 512-hw chunk, single 64 KiB buffer, 2 blocks/CU) and
// computes a 128-row half of the 256x256 output. XOR-octet swizzle.
// Register prefetch of the next phase's globals under the current MFMA.
// ---------------------------------------------------------------------------
__global__ __launch_bounds__(512) void k_sgemm(const float* __restrict__ x,
                                               float* __restrict__ part) {
  __shared__ unsigned short Pt[256 * 128];   // 64 KiB
  int bid = blockIdx.x;
  int chunkid = (bid & 7) | ((bid >> 4) << 3);   // 0..127
  int hs = (bid >> 3) & 1;
  int ks = chunkid & 31, b = chunkid >> 5;
  const float* xv = x + ((size_t)(b * HW_ + ks * 512)) * C_;
  int t = threadIdx.x, lane = t & 63, w = t >> 6;   // 8 waves
  int rw = w >> 2, cw = w & 3;                      // 2x4 wave grid on 128x256
  int m0 = hs * 128 + rw * 64;
  int n0 = cw * 64;
  int l15 = lane & 15, l4 = lane >> 4;
  int s_cq  = (lane >> 3) | (w << 3);       // 0..63: which c-quad
  int s_hpl = lane & 7;                     // low 3 bits of hw-pair
  floatx4 acc[4][4];
  floatx4 z = {0.f, 0.f, 0.f, 0.f};
#pragma unroll
  for (int i = 0; i < 4; i++)
#pragma unroll
    for (int j = 0; j < 4; j++) acc[i][j] = z;

  // stage phase 0 (load -> cvt -> ds_write)
#pragma unroll
  for (int e = 0; e < 8; e++) {
    int hp = s_hpl | (e << 3);
    const float* src = xv + ((size_t)(hp * 2)) * C_ + s_cq * 4;
    float4 v0 = *(const float4*)src;
    float4 v1 = *(const float4*)(src + C_);
    float a0[4] = {v0.x, v0.y, v0.z, v0.w};
    float a1[4] = {v1.x, v1.y, v1.z, v1.w};
#pragma unroll
    for (int i = 0; i < 4; i++) {
      unsigned u = (unsigned)f2bf(a0[i]) | ((unsigned)f2bf(a1[i]) << 16);
      int r = s_cq * 4 + i;
      int slot = (hp >> 2) ^ (r & 15);
      ((unsigned*)Pt)[r * 64 + slot * 4 + (hp & 3)] = u;
    }
  }
  __syncthreads();

  float4 pA[8], pB[8];
  for (int ph = 0; ph < 4; ph++) {
    if (ph < 3) {
      // issue next phase's global loads early (latency under MFMA below)
#pragma unroll
      for (int e = 0; e < 8; e++) {
        int hp = s_hpl | (e << 3);
        const float* src = xv + ((size_t)((ph + 1) * 128 + hp * 2)) * C_ + s_cq * 4;
        pA[e] = *(const float4*)src;
        pB[e] = *(const float4*)(src + C_);
      }
    }
#pragma unroll
    for (int kk = 0; kk < 4; kk++) {       // 4 k-steps of 32 per phase
      short8 af[4], bfv[4];
      int oct = kk * 4 + l4;
#pragma unroll
      for (int tm = 0; tm < 4; tm++) {
        int row = m0 + tm * 16 + l15;
        af[tm] = *(const short8*)(Pt + row * 128 + ((oct ^ (row & 15)) * 8));
      }
#pragma unroll
      for (int tn = 0; tn < 4; tn++) {
        int row = n0 + tn * 16 + l15;
        bfv[tn] = *(const short8*)(Pt + row * 128 + ((oct ^ (row & 15)) * 8));
      }
#pragma unroll
      for (int tm = 0; tm < 4; tm++)
#pragma unroll
        for (int tn = 0; tn < 4; tn++)
          acc[tm][tn] = __builtin_amdgcn_mfma_f32_16x16x32_bf16(af[tm], bfv[tn],
                                                                acc[tm][tn], 0, 0, 0);
    }
    if (ph < 3) {
      __syncthreads();                     // everyone done reading Pt(ph)
#pragma unroll
      for (int e = 0; e < 8; e++) {
        int hp = s_hpl | (e << 3);
        float a0[4] = {pA[e].x, pA[e].y, pA[e].z, pA[e].w};
        float a1[4] = {pB[e].x, pB[e].y, pB[e].z, pB[e].w};
#pragma unroll
        for (int i = 0; i < 4; i++) {
          unsigned u = (unsigned)f2bf(a0[i]) | ((unsigned)f2bf(a1[i]) << 16);
          int r = s_cq * 4 + i;
          int slot = (hp >> 2) ^ (r & 15);
          ((unsigned*)Pt)[r * 64 + slot * 4 + (hp & 3)] = u;
        }
      }
      __syncthreads();                     // Pt(ph+1) ready
    }
  }
  // epilogue: streaming fp32 partial half-tile [b][ks][m 128-half][256]
  float* pb = part + (size_t)(b * 32 + ks) * 65536;
#pragma unroll
  for (int tm = 0; tm < 4; tm++)
#pragma unroll
    for (int tn = 0; tn < 4; tn++)
#pragma unroll
      for (int r = 0; r < 4; r++) {
        int m = m0 + tm * 16 + l4 * 4 + r;   // C/D: row=(lane>>4)*4+reg
        int n = n0 + tn * 16 + l15;          //      col=lane&15
        pb[m * 256 + n] = acc[tm][tn][r];
      }
}

// K2r: reduce 32 K-partials -> S fp32 [b][256][256]. grid 256 x 256, float4.
__global__ __launch_bounds__(256) void k_sred(const float* __restrict__ part,
                                              float* __restrict__ S) {
  int g = blockIdx.x * 256 + threadIdx.x;     // 0..65535 float4 slots
  int b = g >> 14, off = (g & 16383) * 4;
  const float* p = part + ((size_t)b << 21) + off;
  float4 s = {0.f, 0.f, 0.f, 0.f};
#pragma unroll
  for (int k = 0; k < 32; k++) {
    float4 v = *(const float4*)(p + ((size_t)k << 16));
    s.x += v.x; s.y += v.y; s.z += v.z; s.w += v.w;
  }
  *(float4*)(S + ((size_t)b << 16) + off) = s;
}

// ---------------------------------------------------------------------------
// K3a: SWq = S@Wq, SWk = S@Wk (fp32, 64x64 tiles). grid 128 = b(4)*mt(4)*nt(8).
// ---------------------------------------------------------------------------
__global__ __launch_bounds__(256) void k_gemm_sw(const float* __restrict__ S,
                                                 const float* __restrict__ Wq,
                                                 const float* __restrict__ Wk,
                                                 float* __restrict__ SWq,
                                                 float* __restrict__ SWk) {
  __shared__ float Ast[16][68];
  __shared__ float Bs[16][68];
  int bid = blockIdx.x;
  int nt = bid & 7, mt = (bid >> 3) & 3, b = bid >> 5;
  int mb = mt * 64;
  const float* Wsel = (nt < 4) ? Wq : Wk;
  int nb = (nt & 3) * 64;
  int t = threadIdx.x, tx = t & 15, ty = t >> 4;
  float acc[4][4] = {};
  for (int kt = 0; kt < 16; kt++) {
    {
      int row = t >> 2, kq = t & 3;
      float4 v = *(const float4*)(S + ((size_t)(b * C_ + mb + row)) * C_ + kt * 16 + kq * 4);
      Ast[kq * 4 + 0][row] = v.x; Ast[kq * 4 + 1][row] = v.y;
      Ast[kq * 4 + 2][row] = v.z; Ast[kq * 4 + 3][row] = v.w;
    }
    {
      int kk = t >> 4, n4 = t & 15;
      float4 v = *(const float4*)(Wsel + ((size_t)(kt * 16 + kk)) * C_ + nb + n4 * 4);
      *(float4*)&Bs[kk][n4 * 4] = v;
    }
    __syncthreads();
#pragma unroll
    for (int k = 0; k < 16; k++) {
      float4 a4 = *(const float4*)&Ast[k][ty * 4];
      float4 b4 = *(const float4*)&Bs[k][tx * 4];
      float a[4] = {a4.x, a4.y, a4.z, a4.w};
      float bb[4] = {b4.x, b4.y, b4.z, b4.w};
#pragma unroll
      for (int i = 0; i < 4; i++)
#pragma unroll
        for (int j = 0; j < 4; j++) acc[i][j] += a[i] * bb[j];
    }
    __syncthreads();
  }
#pragma unroll
  for (int i = 0; i < 4; i++)
#pragma unroll
    for (int j = 0; j < 4; j++) {
      int row = mb + ty * 4 + i;
      int ng = nt * 64 + tx * 4 + j;
      if (ng < 256) SWq[((size_t)(b * C_ + row)) * C_ + ng] = acc[i][j];
      else          SWk[((size_t)(b * C_ + row)) * C_ + ng - 256] = acc[i][j];
    }
}

// ---------------------------------------------------------------------------
// K3f: fused G_h + norms + softmax + U_h. grid 32 = (b,h), 256 thr.
// ---------------------------------------------------------------------------
__global__ __launch_bounds__(256) void k_fuse(const float* __restrict__ Wq,
                                              const float* __restrict__ Wk,
                                              const float* __restrict__ SWq,
                                              const float* __restrict__ SWk,
                                              const float* __restrict__ Wout,
                                              float* __restrict__ U) {
  __shared__ float Wqh[256][32];    // 32 KiB (reused as Wo[32][256] for U phase)
  __shared__ float Wkh[256][32];
  __shared__ float SWqh[256][32];
  __shared__ float SWkh[256][32];   // total 128 KiB
  __shared__ float Lg[32][33];
  __shared__ float qp[8][32], kp[8][32], qin[32], kin[32];
  int b = blockIdx.x >> 3, h = blockIdx.x & 7;
  int t = threadIdx.x;
  int col = t & 31, rgrp = t >> 5;               // 8 rows per sweep
  for (int r0 = 0; r0 < 256; r0 += 8) {
    int row = r0 + rgrp;
    Wqh[row][col]  = Wq[(size_t)row * C_ + h * 32 + col];
    Wkh[row][col]  = Wk[(size_t)row * C_ + h * 32 + col];
    SWqh[row][col] = SWq[((size_t)(b * C_ + row)) * C_ + h * 32 + col];
    SWkh[row][col] = SWk[((size_t)(b * C_ + row)) * C_ + h * 32 + col];
  }
  __syncthreads();
  {
    float g[4] = {0.f, 0.f, 0.f, 0.f};
    for (int k = 0; k < 256; k++) {
      float swk = SWkh[k][col];
#pragma unroll
      for (int r = 0; r < 4; r++) g[r] += Wqh[k][rgrp + 8 * r] * swk;
    }
#pragma unroll
    for (int r = 0; r < 4; r++) Lg[rgrp + 8 * r][col] = g[r];
  }
  {
    float sq = 0.f, sk = 0.f;
    for (int k = rgrp * 32; k < rgrp * 32 + 32; k++) {
      sq += Wqh[k][col] * SWqh[k][col];
      sk += Wkh[k][col] * SWkh[k][col];
    }
    qp[rgrp][col] = sq;
    kp[rgrp][col] = sk;
  }
  __syncthreads();
  if (t < 32) {
    float a = 0.f;
#pragma unroll
    for (int p = 0; p < 8; p++) a += qp[p][t];
    qin[t] = rsqrtf(a);
  } else if (t < 64) {
    int j = t - 32;
    float a = 0.f;
#pragma unroll
    for (int p = 0; p < 8; p++) a += kp[p][j];
    kin[j] = rsqrtf(a);
  }
  __syncthreads();
  if (t < 32) {
    float row[32];
    float mx = -1e30f;
#pragma unroll
    for (int j = 0; j < 32; j++) {
      row[j] = Lg[t][j] * qin[t] * kin[j] * 0.0078125f;   // /sqrt(16384)
      mx = fmaxf(mx, row[j]);
    }
    float sum = 0.f;
#pragma unroll
    for (int j = 0; j < 32; j++) { row[j] = __expf(row[j] - mx); sum += row[j]; }
    float inv = 1.0f / sum;
#pragma unroll
    for (int j = 0; j < 32; j++) Lg[t][j] = row[j] * inv;
  }
  __syncthreads();
  float (*Wo)[256] = reinterpret_cast<float(*)[256]>(&Wqh[0][0]);
#pragma unroll
  for (int r = 0; r < 32; r++) Wo[r][t] = Wout[((size_t)(h * 32 + r)) * C_ + t];
  __syncthreads();
  for (int j = 0; j < 32; j++) {
    float a = 0.f;
#pragma unroll
    for (int i2 = 0; i2 < 32; i2++) a += Lg[i2][j] * Wo[i2][t];
    U[((size_t)(b * C_ + h * 32 + j)) * C_ + t] = a;
  }
}

// ---------------------------------------------------------------------------
// K3e: W3 = Wv @ U[b], emitted transposed bf16: W3bT[b][n][c]. grid 64.
// ---------------------------------------------------------------------------
__global__ __launch_bounds__(256) void k_gemm_w3(const float* __restrict__ Wv,
                                                 const float* __restrict__ U,
                                                 unsigned short* __restrict__ W3bT) {
  __shared__ float Ast[16][68];
  __shared__ float Bs[16][68];
  int bid = blockIdx.x;
  int nt = bid & 3, mt = (bid >> 2) & 3, b = bid >> 4;
  int mb = mt * 64, nb = nt * 64;
  int t = threadIdx.x, tx = t & 15, ty = t >> 4;
  float acc[4][4] = {};
  for (int kt = 0; kt < 16; kt++) {
    {
      int row = t >> 2, kq = t & 3;
      float4 v = *(const float4*)(Wv + ((size_t)(mb + row)) * C_ + kt * 16 + kq * 4);
      Ast[kq * 4 + 0][row] = v.x; Ast[kq * 4 + 1][row] = v.y;
      Ast[kq * 4 + 2][row] = v.z; Ast[kq * 4 + 3][row] = v.w;
    }
    {
      int kk = t >> 4, n4 = t & 15;
      float4 v = *(const float4*)(U + ((size_t)(b * C_ + kt * 16 + kk)) * C_ + nb + n4 * 4);
      *(float4*)&Bs[kk][n4 * 4] = v;
    }
    __syncthreads();
#pragma unroll
    for (int k = 0; k < 16; k++) {
      float4 a4 = *(const float4*)&Ast[k][ty * 4];
      float4 b4 = *(const float4*)&Bs[k][tx * 4];
      float a[4] = {a4.x, a4.y, a4.z, a4.w};
      float bb[4] = {b4.x, b4.y, b4.z, b4.w};
#pragma unroll
      for (int i = 0; i < 4; i++)
#pragma unroll
        for (int j = 0; j < 4; j++) acc[i][j] += a[i] * bb[j];
    }
    __syncthreads();
  }
#pragma unroll
  for (int i = 0; i < 4; i++)
#pragma unroll
    for (int j = 0; j < 4; j++)
      W3bT[((size_t)(b * C_ + nb + tx * 4 + j)) * C_ + mb + ty * 4 + i] = f2bf(acc[i][j]);
}

// ---------------------------------------------------------------------------
// K4: out = x @ W3[b], fp32 out. grid 1024 = mtile(512) x ntile(2), remapped
// so the ntile pair of an mtile sits 8 bids apart (same XCD -> A-panel L2
// shared). BM=128, BN=128, BK=32, 8 stages. A staged fp32 via
// global_load_lds (4-unit XOR swizzle per 8 rows), B staged bf16 likewise.
// acc[4][4], LDS 24 KiB -> 4 blocks/CU, 16 waves/CU (Little's-law fix).
// ---------------------------------------------------------------------------
__global__ __launch_bounds__(256) void k_out(const float* __restrict__ x,
                                             const unsigned short* __restrict__ W3bT,
                                             float* __restrict__ out) {
  __shared__ float Atf[128 * 32];           // 16 KiB fp32 A tile (swizzled)
  __shared__ unsigned short Bt[128 * 32];   // 8 KiB bf16 B tile (swizzled)
  int bid = blockIdx.x;
  int ntile = (bid >> 3) & 1;
  int mtile = (bid & 7) | ((bid >> 4) << 3);   // 0..511
  int b = mtile >> 7;
  const float* Ax = x + (size_t)mtile * 128 * C_;
  const unsigned short* Bb = W3bT + (size_t)b * C_ * C_ + (size_t)ntile * 128 * C_;
  int t = threadIdx.x, lane = t & 63, w = t >> 6;
  int hf = w >> 1, c2 = w & 1;                 // wave -> 64x64 quadrant
  int l15 = lane & 15, l4 = lane >> 4;
  int a_row_l = lane >> 3, a_u = lane & 7;     // A staging lane split
  int b_row_l = lane >> 2, b_o = lane & 3;     // B staging lane split
  floatx4 acc[4][4];
  floatx4 z = {0.f, 0.f, 0.f, 0.f};
#pragma unroll
  for (int i = 0; i < 4; i++)
#pragma unroll
    for (int j = 0; j < 4; j++) acc[i][j] = z;

  for (int s = 0; s < 8; s++) {
    if (s) __syncthreads();
    // A: 128 rows x 8 fp32-units; 16 issues (4/wave). Linear LDS dest,
    // pre-swizzled source unit usrc = u ^ (row&7).
#pragma unroll
    for (int i = 0; i < 4; i++) {
      int j = w * 4 + i;                   // 0..15
      int row = j * 8 + a_row_l;           // 0..127
      int usrc = a_u ^ (row & 7);
      gl_lds16f(Ax + (size_t)row * C_ + s * 32 + usrc * 4, Atf + j * 256);
    }
    // B: 128 rows x 4 octets; 8 issues (2/wave). srcoct = oct ^ (row&3).
#pragma unroll
    for (int i = 0; i < 2; i++) {
      int j = w * 2 + i;                   // 0..7
      int row = j * 16 + b_row_l;          // 0..127
      int srcoct = b_o ^ (row & 3);
      gl_lds16(Bb + (size_t)row * C_ + s * 32 + srcoct * 8, Bt + j * 512);
    }
    __syncthreads();
    // compute: one k-step of 32 per stage
    short8 af[4], bfv[4];
#pragma unroll
    for (int tm = 0; tm < 4; tm++) {
      int row = hf * 64 + tm * 16 + l15;
      int u0 = (l4 * 2) ^ (row & 7);
      int u1 = (l4 * 2 + 1) ^ (row & 7);
      float4 f0 = *(const float4*)(Atf + row * 32 + u0 * 4);
      float4 f1 = *(const float4*)(Atf + row * 32 + u1 * 4);
      short8 v;
      v[0] = (short)f2bf(f0.x); v[1] = (short)f2bf(f0.y);
      v[2] = (short)f2bf(f0.z); v[3] = (short)f2bf(f0.w);
      v[4] = (short)f2bf(f1.x); v[5] = (short)f2bf(f1.y);
      v[6] = (short)f2bf(f1.z); v[7] = (short)f2bf(f1.w);
      af[tm] = v;
    }
#pragma unroll
    for (int tn = 0; tn < 4; tn++) {
      int row = c2 * 64 + tn * 16 + l15;
      bfv[tn] = *(const short8*)(Bt + row * 32 + ((l4 ^ (row & 3)) * 8));
    }
#pragma unroll
    for (int tm = 0; tm < 4; tm++)
#pragma unroll
      for (int tn = 0; tn < 4; tn++)
        acc[tm][tn] = __builtin_amdgcn_mfma_f32_16x16x32_bf16(af[tm], bfv[tn],
                                                              acc[tm][tn], 0, 0, 0);
  }
  float* ob = out + (size_t)mtile * 128 * C_ + ntile * 128;
#pragma unroll
  for (int tm = 0; tm < 4; tm++)
#pragma unroll
    for (int tn = 0; tn < 4; tn++)
#pragma unroll
      for (int r = 0; r < 4; r++) {
        int m = hf * 64 + tm * 16 + l4 * 4 + r;
        int n = c2 * 64 + tn * 16 + l15;
        ob[(size_t)m * C_ + n] = acc[tm][tn][r];
      }
}

// ---------------------------------------------------------------------------
extern "C" void kernel_launch(void* const* d_in, const int* in_sizes, int n_in,
                              void* d_out, int out_size, void* d_ws, size_t ws_size,
                              hipStream_t stream) {
  const float* x    = (const float*)d_in[0];
  const float* Wq   = (const float*)d_in[1];
  const float* Wk   = (const float*)d_in[2];
  const float* Wv   = (const float*)d_in[3];
  const float* Wout = (const float*)d_in[4];
  float* out = (float*)d_out;

  // workspace carve-up (~36.5 MiB)
  float* part = (float*)d_ws;                           // 4*32*256*256 fp32 = 32 MiB
  float* S    = part + (size_t)8388608;                 // 1 MiB
  float* SWq  = S + 262144;                             // 1 MiB
  float* SWk  = SWq + 262144;                           // 1 MiB
  float* U    = SWk + 262144;                           // 1 MiB
  unsigned short* W3bT = (unsigned short*)(U + 262144); // 512 KiB

  k_sgemm<<<dim3(256), dim3(512), 0, stream>>>(x, part);
  k_sred<<<dim3(256), dim3(256), 0, stream>>>(part, S);
  k_gemm_sw<<<dim3(128), dim3(256), 0, stream>>>(S, Wq, Wk, SWq, SWk);
  k_fuse<<<dim3(32), dim3(256), 0, stream>>>(Wq, Wk, SWq, SWk, Wout, U);
  k_gemm_w3<<<dim3(64), dim3(256), 0, stream>>>(Wv, U, W3bT);
  k_out<<<dim3(1024), dim3(256), 0, stream>>>(x, W3bT, out);
}